// Round 1
// baseline (234.265 us; speedup 1.0000x reference)
//
#include <hip/hip_runtime.h>

#define HW_TOTAL 16384
#define C2 128
#define TSTEPS 16
#define PPB 8
#define NBLK (HW_TOTAL / PPB)

typedef short bf16x8 __attribute__((ext_vector_type(8)));
typedef float f32x4 __attribute__((ext_vector_type(4)));

__device__ __forceinline__ short f2bf(float f) {
    union { float f; unsigned u; } v; v.f = f;
    unsigned r = v.u + 0x7FFFu + ((v.u >> 16) & 1u);  // RNE
    return (short)(r >> 16);
}
__device__ __forceinline__ float sigmoidf_(float x) { return 1.0f / (1.0f + expf(-x)); }
__device__ __forceinline__ float softplusf_(float x) {
    return fmaxf(x, 0.0f) + log1pf(expf(-fabsf(x)));
}

// ---- Kernel 1: direct DFT of padded 7x7 kernels -> field[hw][c] = (Ar,Ai,Br,Bi) ----
__global__ void field_kernel(const float* __restrict__ Ark, const float* __restrict__ Aik,
                             const float* __restrict__ Brk, const float* __restrict__ Bik,
                             float4* __restrict__ field) {
    __shared__ float2 tw[128];
    __shared__ float tap[4][49];
    const int c = blockIdx.x >> 6;
    const int chunk = blockIdx.x & 63;
    const int t = threadIdx.x;
    if (t < 128) {
        float ph = (float)t * (6.283185307179586f / 128.0f);
        tw[t] = make_float2(cosf(ph), sinf(ph));
    }
    if (t < 49) {
        tap[0][t] = Ark[c * 49 + t];
        tap[1][t] = Aik[c * 49 + t];
        tap[2][t] = Brk[c * 49 + t];
        tap[3][t] = Bik[c * 49 + t];
    }
    __syncthreads();
    const int hw = chunk * 256 + t;
    const int u = hw >> 7, v = hw & 127;
    float Are = 0.f, Aim = 0.f, Bre = 0.f, Bim = 0.f;
#pragma unroll
    for (int p = 0; p < 7; ++p) {
        const int up = (u * (p + 60)) & 127;
#pragma unroll
        for (int q = 0; q < 7; ++q) {
            const int idx = (up + v * (q + 60)) & 127;
            const float twr = tw[idx].x;
            const float twi = -tw[idx].y;           // e^{-i phi}
            const float ar = tap[0][p * 7 + q], ai = tap[1][p * 7 + q];
            const float br = tap[2][p * 7 + q], bi = tap[3][p * 7 + q];
            Are += ar * twr - ai * twi;  Aim += ar * twi + ai * twr;
            Bre += br * twr - bi * twi;  Bim += br * twi + bi * twr;
        }
    }
    const float mag = sqrtf(Are * Are + Aim * Aim + 1e-8f);
    const float scale = 0.95f * sigmoidf_(mag) / (mag + 1e-8f);
    field[hw * 64 + c] = make_float4(Are * scale, Aim * scale, Bre, Bim);
}

// ---- Kernel 2: weights fp32 (k,n) -> bf16 transposed (g,n,k) ----
__global__ void wprep_kernel(const float* __restrict__ Wf, const float* __restrict__ Wi,
                             const float* __restrict__ Wd, ushort* __restrict__ Wt) {
    const int idx = blockIdx.x * 256 + threadIdx.x;   // 0 .. 49151
    const int g = idx >> 14;
    const int r = idx & 16383;
    const int n = r >> 7, k = r & 127;
    const float* W = (g == 0) ? Wf : (g == 1) ? Wi : Wd;
    Wt[idx] = (ushort)f2bf(W[k * 128 + n]);
}

// ---- Kernel 3: fused gates-GEMM + complex SSM recurrence ----
__global__ __launch_bounds__(256, 2) void main_kernel(
    const float* __restrict__ x,
    const float* __restrict__ bfv, const float* __restrict__ biv, const float* __restrict__ bdv,
    const float4* __restrict__ field,
    const ushort* __restrict__ Wt,
    float* __restrict__ out)
{
    __shared__ float xs[2][16][132];   // padded stride 132 -> conflict-free b128 reads
    const int tid  = threadIdx.x;
    const int lane = tid & 63;
    const int wave = tid >> 6;   // 0..3
    const int l15  = lane & 15;
    const int lg   = lane >> 4;  // 0..3

    // persistent weight fragments: wf[gate][half][kstep], 96 VGPR/wave
    bf16x8 wf[3][2][4];
#pragma unroll
    for (int g = 0; g < 3; ++g)
#pragma unroll
        for (int s = 0; s < 2; ++s) {
            const int n = l15 + 16 * (wave + 4 * s);
#pragma unroll
            for (int ks = 0; ks < 4; ++ks) {
                const int k0 = 32 * ks + 8 * lg;
                wf[g][s][ks] = *(const bf16x8*)(Wt + ((g * 128 + n) * 128 + k0));
            }
        }

    const int c0 = l15 + 16 * wave;   // real channel
    const int c1 = c0 + 64;           // imag channel
    const float bf0 = bfv[c0], bf1 = bfv[c1];
    const float bi0 = biv[c0], bi1 = biv[c1];
    const float bd0 = bdv[c0], bd1 = bdv[c1];

    const int srow = tid >> 4;         // staging: batch row 0..15
    const int scol = (tid & 15) * 8;   // 8 floats per thread

    const int hw0 = blockIdx.x * PPB;

    // prologue: stage pixel 0
    float4 pa, pb;
    {
        const float* src = x + ((size_t)srow * HW_TOTAL + hw0) * C2 + scol;
        pa = *(const float4*)(src);
        pb = *(const float4*)(src + 4);
    }
    *(float4*)&xs[0][srow][scol]     = pa;
    *(float4*)&xs[0][srow][scol + 4] = pb;
    __syncthreads();

    int cur = 0;
    for (int pp = 0; pp < PPB; ++pp) {
        const int hw = hw0 + pp;

        if (pp + 1 < PPB) {  // prefetch next pixel into registers
            const float* src = x + ((size_t)srow * HW_TOTAL + (hw + 1)) * C2 + scol;
            pa = *(const float4*)(src);
            pb = *(const float4*)(src + 4);
        }

        // --- GEMM phase: 3 gates x 2 channel-halves, K=128 ---
        f32x4 acc[3][2];
#pragma unroll
        for (int g = 0; g < 3; ++g)
#pragma unroll
            for (int s = 0; s < 2; ++s)
                acc[g][s] = (f32x4){0.f, 0.f, 0.f, 0.f};

#pragma unroll
        for (int ks = 0; ks < 4; ++ks) {
            const float* ap = &xs[cur][l15][8 * lg + 32 * ks];
            const float4 a0 = *(const float4*)ap;
            const float4 a1 = *(const float4*)(ap + 4);
            bf16x8 af;
            af[0] = f2bf(a0.x); af[1] = f2bf(a0.y); af[2] = f2bf(a0.z); af[3] = f2bf(a0.w);
            af[4] = f2bf(a1.x); af[5] = f2bf(a1.y); af[6] = f2bf(a1.z); af[7] = f2bf(a1.w);
#pragma unroll
            for (int g = 0; g < 3; ++g)
#pragma unroll
                for (int s = 0; s < 2; ++s)
                    acc[g][s] = __builtin_amdgcn_mfma_f32_16x16x32_bf16(
                        af, wf[g][s][ks], acc[g][s], 0, 0, 0);
        }

        // --- elementwise gates + T=16 complex recurrence ---
        const float4 fld = field[hw * 64 + c0];
        const float Ar = fld.x, Ai = fld.y, Br = fld.z, Bi = fld.w;

#pragma unroll
        for (int r = 0; r < 4; ++r) {
            const int b = 4 * lg + r;   // D-frag row = batch
            const float fg_r = sigmoidf_(acc[0][0][r] + bf0 + 2.0f);
            const float fg_i = sigmoidf_(acc[0][1][r] + bf1 + 2.0f);
            const float ig_r = sigmoidf_(acc[1][0][r] + bi0);
            const float ig_i = sigmoidf_(acc[1][1][r] + bi1);
            const float dl_r = softplusf_(acc[2][0][r] + bd0) * 0.1f;
            const float dl_i = softplusf_(acc[2][1][r] + bd1) * 0.1f;
            const float xr = xs[cur][b][c0];
            const float xi = xs[cur][b][c1];
            const float bx_r = Br * xr - Bi * xi;
            const float bx_i = Br * xi + Bi * xr;
            const float inp_r = dl_r * ig_r * bx_r;
            const float inp_i = dl_i * ig_i * bx_i;
            float hr = 0.f, hi = 0.f;
#pragma unroll
            for (int t = 0; t < TSTEPS; ++t) {
                const float ahr = Ar * hr - Ai * hi;
                const float ahi = Ar * hi + Ai * hr;
                hr = fmaf(fg_r, ahr, inp_r);
                hi = fmaf(fg_i, ahi, inp_i);
            }
            const size_t obase = ((size_t)b * HW_TOTAL + hw) * C2;
            out[obase + c0] = hr;
            out[obase + c1] = hi;
        }

        if (pp + 1 < PPB) {
            *(float4*)&xs[cur ^ 1][srow][scol]     = pa;
            *(float4*)&xs[cur ^ 1][srow][scol + 4] = pb;
        }
        __syncthreads();
        cur ^= 1;
    }
}

extern "C" void kernel_launch(void* const* d_in, const int* in_sizes, int n_in,
                              void* d_out, int out_size, void* d_ws, size_t ws_size,
                              hipStream_t stream) {
    const float* x      = (const float*)d_in[0];
    const float* Wf     = (const float*)d_in[1];
    const float* bf     = (const float*)d_in[2];
    const float* Wi     = (const float*)d_in[3];
    const float* bi     = (const float*)d_in[4];
    const float* Wd     = (const float*)d_in[5];
    const float* bd     = (const float*)d_in[6];
    const float* A_real = (const float*)d_in[7];
    const float* A_imag = (const float*)d_in[8];
    const float* B_real = (const float*)d_in[9];
    const float* B_imag = (const float*)d_in[10];

    float4* field = (float4*)d_ws;                                       // 16 MiB
    ushort* Wt = (ushort*)((char*)d_ws + (size_t)HW_TOTAL * 64 * 16);    // 96 KiB

    field_kernel<<<dim3(4096), dim3(256), 0, stream>>>(A_real, A_imag, B_real, B_imag, field);
    wprep_kernel<<<dim3(192), dim3(256), 0, stream>>>(Wf, Wi, Wd, Wt);
    main_kernel<<<dim3(NBLK), dim3(256), 0, stream>>>(x, bf, bi, bd, field, Wt, (float*)d_out);
}

// Round 2
// 135.926 us; speedup vs baseline: 1.7235x; 1.7235x over previous
//
#include <hip/hip_runtime.h>

#define HW_TOTAL 16384
#define C2 128
#define TSTEPS 16
#define PPB 8
#define NBLK (HW_TOTAL / PPB)

typedef short bf16x8 __attribute__((ext_vector_type(8)));
typedef float f32x4 __attribute__((ext_vector_type(4)));
typedef unsigned short u16x8 __attribute__((ext_vector_type(8)));

__device__ __forceinline__ unsigned short f2bf(float f) {
    union { float f; unsigned u; } v; v.f = f;
    unsigned r = v.u + 0x7FFFu + ((v.u >> 16) & 1u);  // RNE
    return (unsigned short)(r >> 16);
}
// fast transcendentals: v_exp/v_log/v_rcp based (~1 ulp, fine vs 7.2e-3 abs threshold)
__device__ __forceinline__ float fast_sigmoid(float x) {
    return __builtin_amdgcn_rcpf(1.0f + __expf(-x));
}
__device__ __forceinline__ float fast_softplus(float x) {
    return fmaxf(x, 0.0f) + __logf(1.0f + __expf(-fabsf(x)));
}
__device__ __forceinline__ float sigmoidf_(float x) { return 1.0f / (1.0f + expf(-x)); }

// ---- Kernel 1: direct DFT of padded 7x7 kernels -> field[hw][c] = (Ar,Ai,Br,Bi) ----
__global__ void field_kernel(const float* __restrict__ Ark, const float* __restrict__ Aik,
                             const float* __restrict__ Brk, const float* __restrict__ Bik,
                             float4* __restrict__ field) {
    __shared__ float2 tw[128];
    __shared__ float tap[4][49];
    const int c = blockIdx.x >> 6;
    const int chunk = blockIdx.x & 63;
    const int t = threadIdx.x;
    if (t < 128) {
        float ph = (float)t * (6.283185307179586f / 128.0f);
        tw[t] = make_float2(cosf(ph), sinf(ph));
    }
    if (t < 49) {
        tap[0][t] = Ark[c * 49 + t];
        tap[1][t] = Aik[c * 49 + t];
        tap[2][t] = Brk[c * 49 + t];
        tap[3][t] = Bik[c * 49 + t];
    }
    __syncthreads();
    const int hw = chunk * 256 + t;
    const int u = hw >> 7, v = hw & 127;
    float Are = 0.f, Aim = 0.f, Bre = 0.f, Bim = 0.f;
#pragma unroll
    for (int p = 0; p < 7; ++p) {
        const int up = (u * (p + 60)) & 127;
#pragma unroll
        for (int q = 0; q < 7; ++q) {
            const int idx = (up + v * (q + 60)) & 127;
            const float twr = tw[idx].x;
            const float twi = -tw[idx].y;           // e^{-i phi}
            const float ar = tap[0][p * 7 + q], ai = tap[1][p * 7 + q];
            const float br = tap[2][p * 7 + q], bi = tap[3][p * 7 + q];
            Are += ar * twr - ai * twi;  Aim += ar * twi + ai * twr;
            Bre += br * twr - bi * twi;  Bim += br * twi + bi * twr;
        }
    }
    const float mag = sqrtf(Are * Are + Aim * Aim + 1e-8f);
    const float scale = 0.95f * sigmoidf_(mag) / (mag + 1e-8f);
    field[hw * 64 + c] = make_float4(Are * scale, Aim * scale, Bre, Bim);
}

// ---- Kernel 2: weights fp32 (k,n) -> bf16 transposed (g,n,k) ----
__global__ void wprep_kernel(const float* __restrict__ Wf, const float* __restrict__ Wi,
                             const float* __restrict__ Wd, ushort* __restrict__ Wt) {
    const int idx = blockIdx.x * 256 + threadIdx.x;   // 0 .. 49151
    const int g = idx >> 14;
    const int r = idx & 16383;
    const int n = r >> 7, k = r & 127;
    const float* W = (g == 0) ? Wf : (g == 1) ? Wi : Wd;
    Wt[idx] = f2bf(W[k * 128 + n]);
}

// ---- Kernel 3: fused gates-GEMM + complex SSM recurrence ----
__global__ __launch_bounds__(256, 2) void main_kernel(
    const float* __restrict__ x,
    const float* __restrict__ bfv, const float* __restrict__ biv, const float* __restrict__ bdv,
    const float4* __restrict__ field,
    const ushort* __restrict__ Wt,
    float* __restrict__ out)
{
    __shared__ float  xs[2][16][132];   // fp32 tile for recurrence inputs
    __shared__ ushort xb[2][16][136];   // bf16 tile for MFMA A-frags (stride 136 -> min-round b128)
    const int tid  = threadIdx.x;
    const int lane = tid & 63;
    const int wave = tid >> 6;   // 0..3
    const int l15  = lane & 15;
    const int lg   = lane >> 4;  // 0..3

    // persistent weight fragments: wf[gate][half][kstep]
    bf16x8 wf[3][2][4];
#pragma unroll
    for (int g = 0; g < 3; ++g)
#pragma unroll
        for (int s = 0; s < 2; ++s) {
            const int n = l15 + 16 * (wave + 4 * s);
#pragma unroll
            for (int ks = 0; ks < 4; ++ks) {
                const int k0 = 32 * ks + 8 * lg;
                wf[g][s][ks] = *(const bf16x8*)(Wt + ((g * 128 + n) * 128 + k0));
            }
        }

    const int c0 = l15 + 16 * wave;   // real channel
    const int c1 = c0 + 64;           // imag channel
    const float bf0 = bfv[c0] + 2.0f, bf1 = bfv[c1] + 2.0f;
    const float bi0 = biv[c0], bi1 = biv[c1];
    const float bd0 = bdv[c0], bd1 = bdv[c1];

    const int srow = tid >> 4;         // staging: batch row 0..15
    const int scol = (tid & 15) * 8;   // 8 floats per thread

    const int hw0 = blockIdx.x * PPB;

    // prologue: stage pixel 0
    float4 pa, pb;
    {
        const float* src = x + ((size_t)srow * HW_TOTAL + hw0) * C2 + scol;
        pa = *(const float4*)(src);
        pb = *(const float4*)(src + 4);
    }
    {
        *(float4*)&xs[0][srow][scol]     = pa;
        *(float4*)&xs[0][srow][scol + 4] = pb;
        u16x8 ub;
        ub[0] = f2bf(pa.x); ub[1] = f2bf(pa.y); ub[2] = f2bf(pa.z); ub[3] = f2bf(pa.w);
        ub[4] = f2bf(pb.x); ub[5] = f2bf(pb.y); ub[6] = f2bf(pb.z); ub[7] = f2bf(pb.w);
        *(u16x8*)&xb[0][srow][scol] = ub;
    }
    __syncthreads();

    int cur = 0;
    for (int pp = 0; pp < PPB; ++pp) {
        const int hw = hw0 + pp;

        if (pp + 1 < PPB) {  // prefetch next pixel into registers
            const float* src = x + ((size_t)srow * HW_TOTAL + (hw + 1)) * C2 + scol;
            pa = *(const float4*)(src);
            pb = *(const float4*)(src + 4);
        }

        // --- GEMM phase: 3 gates x 2 channel-halves, K=128 ---
        f32x4 acc[3][2];
#pragma unroll
        for (int g = 0; g < 3; ++g)
#pragma unroll
            for (int s = 0; s < 2; ++s)
                acc[g][s] = (f32x4){0.f, 0.f, 0.f, 0.f};

#pragma unroll
        for (int ks = 0; ks < 4; ++ks) {
            const bf16x8 af = *(const bf16x8*)&xb[cur][l15][8 * lg + 32 * ks];
#pragma unroll
            for (int g = 0; g < 3; ++g)
#pragma unroll
                for (int s = 0; s < 2; ++s)
                    acc[g][s] = __builtin_amdgcn_mfma_f32_16x16x32_bf16(
                        af, wf[g][s][ks], acc[g][s], 0, 0, 0);
        }

        // --- elementwise gates + T=16 complex recurrence ---
        const float4 fld = field[hw * 64 + c0];
        const float Ar = fld.x, Ai = fld.y, Br = fld.z, Bi = fld.w;

#pragma unroll
        for (int r = 0; r < 4; ++r) {
            const int b = 4 * lg + r;   // D-frag row = batch
            const float fg_r = fast_sigmoid(acc[0][0][r] + bf0);
            const float fg_i = fast_sigmoid(acc[0][1][r] + bf1);
            const float ig_r = fast_sigmoid(acc[1][0][r] + bi0);
            const float ig_i = fast_sigmoid(acc[1][1][r] + bi1);
            const float dl_r = fast_softplus(acc[2][0][r] + bd0) * 0.1f;
            const float dl_i = fast_softplus(acc[2][1][r] + bd1) * 0.1f;
            const float xr = xs[cur][b][c0];
            const float xi = xs[cur][b][c1];
            const float inp_r = dl_r * ig_r * (Br * xr - Bi * xi);
            const float inp_i = dl_i * ig_i * (Br * xi + Bi * xr);
            // fold gates into the 2x2 matrix: 4 fma per step
            const float Crr = fg_r * Ar, Cri = fg_r * Ai;
            const float Cir = fg_i * Ai, Cii = fg_i * Ar;
            float hr = inp_r, hi = inp_i;   // h after step 1 (h0 = 0)
#pragma unroll
            for (int t = 1; t < TSTEPS; ++t) {
                const float nr = fmaf(Crr, hr, fmaf(-Cri, hi, inp_r));
                const float ni = fmaf(Cir, hr, fmaf(Cii, hi, inp_i));
                hr = nr; hi = ni;
            }
            const size_t obase = ((size_t)b * HW_TOTAL + hw) * C2;
            out[obase + c0] = hr;
            out[obase + c1] = hi;
        }

        if (pp + 1 < PPB) {
            *(float4*)&xs[cur ^ 1][srow][scol]     = pa;
            *(float4*)&xs[cur ^ 1][srow][scol + 4] = pb;
            u16x8 ub;
            ub[0] = f2bf(pa.x); ub[1] = f2bf(pa.y); ub[2] = f2bf(pa.z); ub[3] = f2bf(pa.w);
            ub[4] = f2bf(pb.x); ub[5] = f2bf(pb.y); ub[6] = f2bf(pb.z); ub[7] = f2bf(pb.w);
            *(u16x8*)&xb[cur ^ 1][srow][scol] = ub;
        }
        __syncthreads();
        cur ^= 1;
    }
}

extern "C" void kernel_launch(void* const* d_in, const int* in_sizes, int n_in,
                              void* d_out, int out_size, void* d_ws, size_t ws_size,
                              hipStream_t stream) {
    const float* x      = (const float*)d_in[0];
    const float* Wf     = (const float*)d_in[1];
    const float* bf     = (const float*)d_in[2];
    const float* Wi     = (const float*)d_in[3];
    const float* bi     = (const float*)d_in[4];
    const float* Wd     = (const float*)d_in[5];
    const float* bd     = (const float*)d_in[6];
    const float* A_real = (const float*)d_in[7];
    const float* A_imag = (const float*)d_in[8];
    const float* B_real = (const float*)d_in[9];
    const float* B_imag = (const float*)d_in[10];

    float4* field = (float4*)d_ws;                                       // 16 MiB
    ushort* Wt = (ushort*)((char*)d_ws + (size_t)HW_TOTAL * 64 * 16);    // 96 KiB

    field_kernel<<<dim3(4096), dim3(256), 0, stream>>>(A_real, A_imag, B_real, B_imag, field);
    wprep_kernel<<<dim3(192), dim3(256), 0, stream>>>(Wf, Wi, Wd, Wt);
    main_kernel<<<dim3(NBLK), dim3(256), 0, stream>>>(x, bf, bi, bd, field, Wt, (float*)d_out);
}